// Round 9
// baseline (882.583 us; speedup 1.0000x reference)
//
#include <hip/hip_runtime.h>

// LIF layer: Wx = x @ W^T, then sequential scan over T.
// fp32 end-to-end; per-(t,h) sequential-k fma chain and scan expression
// identical to R0..R8 (absmax == 0.0).
//
// R9: scan re-decomposed for WRITE contiguity. Ledger: five scan variants
// (reg-pipeline, P/C ring, nt stores, NT loads, contiguous-read ring) all
// pinned at ~1.2 TB/s; the invariant was 256B@2KB-stride spike writes from
// 512 fragmented per-(b,slab) streams. Now: ONE block per batch row b --
// out[b] is a contiguous [T,H]=2MB range, so the block's collective read
// AND write streams are fully contiguous (8 waves cover each 2KB t-row).
// 64 blocks x 512 threads, R1's register pipeline (PF=32), in-place.
// In-flight 4MB > 2.4MB Little's-law req for 6.3 TB/s.
// GEMM: exact R6 kernel (stable 388us, 57% of the 219us fp32-fma floor;
// deeper pipelining refuted by R2/R7 VGPR blowup).

#define ALPHA_LO_F ((float)0.8187307530779818)   // exp(-1/5)
#define ALPHA_HI_F ((float)0.9607894391523232)   // exp(-1/25)

typedef float v4f __attribute__((ext_vector_type(4)));

// ---------------------------------------------------------------------------
// Kernel 1: fp32 NT GEMM, 128x128 tile, BK=16, 256 threads, 8x8 acc/thread.
// LDS As[k][m], Bs[k][n]; staging scatter-writes 2-way aliased (free, m136).
// A reads: 4 unique 16B addrs broadcast x16 lanes = clean. B reads: 4+4 col
// split -> 16 contiguous 16B chunks, worst 2-way at the 128B wrap.
// ---------------------------------------------------------------------------
#define TM 128
#define TN 128
#define TK 16
__global__ __launch_bounds__(256) void gemm_nt_f32(
    const float* __restrict__ A,   // [M, K]
    const float* __restrict__ B,   // [N, K]
    float* __restrict__ C,         // [M, N]
    int M, int N, int K)
{
    __shared__ float As[TK][TM];
    __shared__ float Bs[TK][TN];

    const int tid = threadIdx.x;
    const int m0  = blockIdx.y * TM;
    const int n0  = blockIdx.x * TN;

    const int lrow = tid >> 1;
    const int lkq  = (tid & 1) * 8;

    const int tm = tid >> 4;     // 0..15
    const int tn = tid & 15;     // 0..15

    float acc[8][8] = {};

    const float* Arow = A + (size_t)(m0 + lrow) * K + lkq;
    const float* Brow = B + (size_t)(n0 + lrow) * K + lkq;

    for (int k0 = 0; k0 < K; k0 += TK) {
        float4 av0 = *(const float4*)(Arow + k0);
        float4 av1 = *(const float4*)(Arow + k0 + 4);
        float4 bv0 = *(const float4*)(Brow + k0);
        float4 bv1 = *(const float4*)(Brow + k0 + 4);
        As[lkq + 0][lrow] = av0.x;  As[lkq + 1][lrow] = av0.y;
        As[lkq + 2][lrow] = av0.z;  As[lkq + 3][lrow] = av0.w;
        As[lkq + 4][lrow] = av1.x;  As[lkq + 5][lrow] = av1.y;
        As[lkq + 6][lrow] = av1.z;  As[lkq + 7][lrow] = av1.w;
        Bs[lkq + 0][lrow] = bv0.x;  Bs[lkq + 1][lrow] = bv0.y;
        Bs[lkq + 2][lrow] = bv0.z;  Bs[lkq + 3][lrow] = bv0.w;
        Bs[lkq + 4][lrow] = bv1.x;  Bs[lkq + 5][lrow] = bv1.y;
        Bs[lkq + 6][lrow] = bv1.z;  Bs[lkq + 7][lrow] = bv1.w;
        __syncthreads();

        #pragma unroll
        for (int k = 0; k < TK; ++k) {
            const float* Ak  = &As[k][tm * 8];
            const float* Bk0 = &Bs[k][tn * 4];        // conflict-free b128
            const float* Bk1 = &Bs[k][64 + tn * 4];   // conflict-free b128
            float4 a0 = *(const float4*)(Ak);
            float4 a1 = *(const float4*)(Ak + 4);
            float4 b0 = *(const float4*)(Bk0);
            float4 b1 = *(const float4*)(Bk1);
            float a[8]  = {a0.x, a0.y, a0.z, a0.w, a1.x, a1.y, a1.z, a1.w};
            float bv[8] = {b0.x, b0.y, b0.z, b0.w, b1.x, b1.y, b1.z, b1.w};
            #pragma unroll
            for (int i = 0; i < 8; ++i) {
                #pragma unroll
                for (int j = 0; j < 8; ++j)
                    acc[i][j] = __builtin_fmaf(a[i], bv[j], acc[i][j]);
            }
        }
        __syncthreads();
    }

    #pragma unroll
    for (int i = 0; i < 8; ++i) {
        float* Crow = C + (size_t)(m0 + tm * 8 + i) * N + n0;
        v4f v0, v1;
        v0.x = acc[i][0]; v0.y = acc[i][1]; v0.z = acc[i][2]; v0.w = acc[i][3];
        v1.x = acc[i][4]; v1.y = acc[i][5]; v1.z = acc[i][6]; v1.w = acc[i][7];
        __builtin_nontemporal_store(v0, (v4f*)(Crow + tn * 4));
        __builtin_nontemporal_store(v1, (v4f*)(Crow + 64 + tn * 4));
    }
}

// ---------------------------------------------------------------------------
// Kernel 2: LIF scan, one block per batch row b. blockDim = H (<=1024).
// Thread h owns the (b,h) chain; the BLOCK's collective accesses cover each
// 2KB t-row contiguously, and consecutive t-rows are contiguous in [T,H] --
// fully contiguous 2MB read + 2MB write stream per block. R1's register
// pipeline: issue next PF batch -> chain PF steps -> nt-store -> rotate.
// ---------------------------------------------------------------------------
#define SPF 32
__global__ __launch_bounds__(1024) void lif_scan_wide(
    float* __restrict__ buf,            // [B, T, H]: in = Wx, out = spikes
    const float* __restrict__ alpha,    // [H]
    const float* __restrict__ u0,       // [B, H]
    const float* __restrict__ s0,       // [B, H]
    int B, int T, int H)
{
    const int h = threadIdx.x;
    const int b = blockIdx.x;
    if (h >= H) return;

    float al = alpha[h];
    al = fminf(fmaxf(al, ALPHA_LO_F), ALPHA_HI_F);
    const float oma = 1.0f - al;

    float u = u0[(size_t)b * H + h];
    float s = s0[(size_t)b * H + h];

    const size_t sH = (size_t)H;
    size_t idx = (size_t)b * T * H + h;

    float cur[SPF], nxt[SPF];
    #pragma unroll
    for (int j = 0; j < SPF; ++j) cur[j] = buf[idx + (size_t)j * sH];

    for (int t0 = 0; t0 + SPF <= T; t0 += SPF) {
        const size_t nidx = idx + (size_t)SPF * sH;
        if (t0 + SPF < T) {
            #pragma unroll
            for (int j = 0; j < SPF; ++j) nxt[j] = buf[nidx + (size_t)j * sH];
        }
        #pragma unroll
        for (int j = 0; j < SPF; ++j) {
            u = al * (u - s) + oma * cur[j];          // same fp32 expr as R0..R8
            s = (u - 1.0f > 0.0f) ? 1.0f : 0.0f;
            cur[j] = s;
        }
        #pragma unroll
        for (int j = 0; j < SPF; ++j)
            __builtin_nontemporal_store(cur[j], &buf[idx + (size_t)j * sH]);
        #pragma unroll
        for (int j = 0; j < SPF; ++j) cur[j] = nxt[j];
        idx = nidx;
    }
    // tail (T % SPF != 0) -- not taken for T=1024
    for (int t = (T / SPF) * SPF; t < T; ++t) {
        float w = buf[(size_t)b * T * H + (size_t)t * H + h];
        u = al * (u - s) + oma * w;
        s = (u - 1.0f > 0.0f) ? 1.0f : 0.0f;
        __builtin_nontemporal_store(s, &buf[(size_t)b * T * H + (size_t)t * H + h]);
    }
}

// ---------------------------------------------------------------------------
// Fallback scan (R6-verified producer/consumer, per-(b,slab)) for shapes the
// wide kernel can't take (H > 1024 or H % 64 != 0).
// ---------------------------------------------------------------------------
#define C_T  64
#define NBUF 4
__global__ __launch_bounds__(320) void lif_scan_ip(
    float* __restrict__ buf,
    const float* __restrict__ alpha,
    const float* __restrict__ u0,
    const float* __restrict__ s0,
    int B, int T, int H)
{
    __shared__ float S[NBUF][C_T][64];

    const int tid  = threadIdx.x;
    const int wid  = tid >> 6;
    const int lane = tid & 63;
    const int b    = blockIdx.y;
    const int h0   = blockIdx.x * 64;
    const int nch  = T / C_T;

    float* base = buf + (size_t)b * T * H + h0;

    if (wid == 0) {
        const int h = h0 + lane;
        float al = alpha[h];
        al = fminf(fmaxf(al, ALPHA_LO_F), ALPHA_HI_F);
        const float oma = 1.0f - al;
        float u = u0[(size_t)b * H + h];
        float s = s0[(size_t)b * H + h];

        for (int j = 0; j < nch; ++j) {
            asm volatile("s_barrier" ::: "memory");
            const float* Sj = &S[j & (NBUF - 1)][0][0] + lane;
            float* orow = base + (size_t)j * C_T * H + lane;
            for (int tb = 0; tb < C_T; tb += 16) {
                float w[16];
                #pragma unroll
                for (int tt = 0; tt < 16; ++tt)
                    w[tt] = Sj[(tb + tt) * 64];
                #pragma unroll
                for (int tt = 0; tt < 16; ++tt) {
                    u = al * (u - s) + oma * w[tt];
                    s = (u - 1.0f > 0.0f) ? 1.0f : 0.0f;
                    w[tt] = s;
                }
                #pragma unroll
                for (int tt = 0; tt < 16; ++tt)
                    __builtin_nontemporal_store(w[tt], &orow[(size_t)(tb + tt) * H]);
            }
            asm volatile("s_waitcnt lgkmcnt(0)" ::: "memory");
            asm volatile("s_barrier" ::: "memory");
        }
    } else {
        const int lw = wid - 1;

        #define ISSUE_CHUNK(c)                                                  \
            {                                                                   \
                const int cc = (c);                                             \
                char* sb = (char*)&S[cc & (NBUF - 1)][0][0];                    \
                _Pragma("unroll")                                               \
                for (int q = 0; q < 4; ++q) {                                   \
                    const int i = lw + 4 * q;                                   \
                    const int t = cc * C_T + i * 4 + (lane >> 4);               \
                    const float* g = base + (size_t)t * H + (lane & 15) * 4;    \
                    __builtin_amdgcn_global_load_lds(                           \
                        (const __attribute__((address_space(1))) unsigned int*)g, \
                        (__attribute__((address_space(3))) unsigned int*)(sb + i * 1024), \
                        16, 0, 0);                                              \
                }                                                               \
            }

        for (int c = 0; c < NBUF - 1; ++c) ISSUE_CHUNK(c)

        for (int j = 0; j < nch; ++j) {
            const int c = j + NBUF - 1;
            if (c < nch) ISSUE_CHUNK(c)
            if (j < nch - 3)       asm volatile("s_waitcnt vmcnt(12)" ::: "memory");
            else if (j == nch - 3) asm volatile("s_waitcnt vmcnt(8)"  ::: "memory");
            else if (j == nch - 2) asm volatile("s_waitcnt vmcnt(4)"  ::: "memory");
            else                   asm volatile("s_waitcnt vmcnt(0)"  ::: "memory");
            asm volatile("s_barrier" ::: "memory");
            asm volatile("s_barrier" ::: "memory");
        }
        #undef ISSUE_CHUNK
    }
}

extern "C" void kernel_launch(void* const* d_in, const int* in_sizes, int n_in,
                              void* d_out, int out_size, void* d_ws, size_t ws_size,
                              hipStream_t stream) {
    const float* x     = (const float*)d_in[0];   // [B, T, I]
    const float* W     = (const float*)d_in[1];   // [H, I]
    const float* alpha = (const float*)d_in[2];   // [H]
    const float* u0    = (const float*)d_in[3];   // [B, H]
    const float* s0    = (const float*)d_in[4];   // [B, H]
    float* out = (float*)d_out;                   // [B, T, H]

    const int H = in_sizes[2];
    const int I = in_sizes[1] / H;
    const int B = in_sizes[3] / H;
    const int T = in_sizes[0] / (B * I);
    const int M = B * T;

    // 1) Wx -> d_out (exactly [B,T,H] f32; reused in-place by the scan)
    dim3 grid1(H / TN, M / TM);
    gemm_nt_f32<<<grid1, 256, 0, stream>>>(x, W, out, M, H, I);

    // 2) scan over T, in-place
    if (H <= 1024 && (H & 63) == 0 && T >= SPF) {
        lif_scan_wide<<<B, H, 0, stream>>>(out, alpha, u0, s0, B, T, H);
    } else {
        dim3 grid2(H / 64, B);
        lif_scan_ip<<<grid2, 320, 0, stream>>>(out, alpha, u0, s0, B, T, H);
    }
}

// Round 10
// 622.698 us; speedup vs baseline: 1.4174x; 1.4174x over previous
//
#include <hip/hip_runtime.h>

// LIF layer: Wx = x @ W^T (x:[B,T,I] f32, W:[H,I] f32), then sequential scan
// over T:  u = al*(u - s) + (1-al)*wx ;  s = (u - 1 > 0) ? 1 : 0.
// fp32 end-to-end; accumulation order (sequential-k fma per (m,n)) bitwise-
// identical to R0..R9 (absmax == 0.0).
//
// R10 = R3-exact (best known, 583us) with ONE change: the GEMM is launched as
// TWO half-M dispatches (row-parallel, same code/k-order per row -> bitwise
// identical). Purpose: each gemm half (~190us) drops below the scan (~205us),
// so the scan FINALLY appears in rocprof's top-5 and we get real counters.
// 10 rounds of scan theories (depth, cache policy, read contiguity, write
// contiguity) were all refuted by subtraction-only evidence; no more edits
// without counter data.

#define ALPHA_LO_F ((float)0.8187307530779818)   // exp(-1/5)
#define ALPHA_HI_F ((float)0.9607894391523232)   // exp(-1/25)

// ---------------------------------------------------------------------------
// Kernel 1: fp32 NT GEMM, 128x128 tile, BK=16, 256 threads, 8x8 acc/thread.
// LDS As[k][m], Bs[k][n]; staging scatter-writes 2-way aliased (free, m136).
// A reads: 4 unique 16B addrs broadcast x16 = clean. B reads: 4+4 col split
// -> 16 contiguous 16B chunks, worst 2-way at the 128B wrap.
// ---------------------------------------------------------------------------
#define TM 128
#define TN 128
#define TK 16
__global__ __launch_bounds__(256) void gemm_nt_f32(
    const float* __restrict__ A,   // [M, K]
    const float* __restrict__ B,   // [N, K]
    float* __restrict__ C,         // [M, N]
    int M, int N, int K)
{
    __shared__ float As[TK][TM];
    __shared__ float Bs[TK][TN];

    const int tid = threadIdx.x;
    const int m0  = blockIdx.y * TM;
    const int n0  = blockIdx.x * TN;

    const int lrow = tid >> 1;
    const int lkq  = (tid & 1) * 8;

    const int tm = tid >> 4;     // 0..15
    const int tn = tid & 15;     // 0..15

    float acc[8][8] = {};

    const float* Arow = A + (size_t)(m0 + lrow) * K + lkq;
    const float* Brow = B + (size_t)(n0 + lrow) * K + lkq;

    for (int k0 = 0; k0 < K; k0 += TK) {
        float4 av0 = *(const float4*)(Arow + k0);
        float4 av1 = *(const float4*)(Arow + k0 + 4);
        float4 bv0 = *(const float4*)(Brow + k0);
        float4 bv1 = *(const float4*)(Brow + k0 + 4);
        As[lkq + 0][lrow] = av0.x;  As[lkq + 1][lrow] = av0.y;
        As[lkq + 2][lrow] = av0.z;  As[lkq + 3][lrow] = av0.w;
        As[lkq + 4][lrow] = av1.x;  As[lkq + 5][lrow] = av1.y;
        As[lkq + 6][lrow] = av1.z;  As[lkq + 7][lrow] = av1.w;
        Bs[lkq + 0][lrow] = bv0.x;  Bs[lkq + 1][lrow] = bv0.y;
        Bs[lkq + 2][lrow] = bv0.z;  Bs[lkq + 3][lrow] = bv0.w;
        Bs[lkq + 4][lrow] = bv1.x;  Bs[lkq + 5][lrow] = bv1.y;
        Bs[lkq + 6][lrow] = bv1.z;  Bs[lkq + 7][lrow] = bv1.w;
        __syncthreads();

        #pragma unroll
        for (int k = 0; k < TK; ++k) {
            const float* Ak  = &As[k][tm * 8];
            const float* Bk0 = &Bs[k][tn * 4];        // conflict-free b128
            const float* Bk1 = &Bs[k][64 + tn * 4];   // conflict-free b128
            float4 a0 = *(const float4*)(Ak);
            float4 a1 = *(const float4*)(Ak + 4);
            float4 b0 = *(const float4*)(Bk0);
            float4 b1 = *(const float4*)(Bk1);
            float a[8]  = {a0.x, a0.y, a0.z, a0.w, a1.x, a1.y, a1.z, a1.w};
            float bv[8] = {b0.x, b0.y, b0.z, b0.w, b1.x, b1.y, b1.z, b1.w};
            #pragma unroll
            for (int i = 0; i < 8; ++i) {
                #pragma unroll
                for (int j = 0; j < 8; ++j)
                    acc[i][j] = __builtin_fmaf(a[i], bv[j], acc[i][j]);
            }
        }
        __syncthreads();
    }

    #pragma unroll
    for (int i = 0; i < 8; ++i) {
        float* Crow = C + (size_t)(m0 + tm * 8 + i) * N + n0;
        float4 v0, v1;
        v0.x = acc[i][0]; v0.y = acc[i][1]; v0.z = acc[i][2]; v0.w = acc[i][3];
        v1.x = acc[i][4]; v1.y = acc[i][5]; v1.z = acc[i][6]; v1.w = acc[i][7];
        *(float4*)(Crow + tn * 4)      = v0;
        *(float4*)(Crow + 64 + tn * 4) = v1;
    }
}

// ---------------------------------------------------------------------------
// Kernel 2: LIF scan, producer/consumer (R3-exact).
// Block = 320 threads (5 waves) per (b, 64-h slab). Wave 0 computes the
// recurrence out of LDS; waves 1..4 stream Wx chunks (C_T=64 t x 64 h =
// 16 KB) into a 4-deep LDS ring with global_load_lds dwordx4; counted vmcnt
// keeps 3 chunks (48 KB/block) in flight across barriers.
// ---------------------------------------------------------------------------
#define C_T  64
#define NBUF 4

__global__ __launch_bounds__(320) void lif_scan(
    float* __restrict__ buf,            // [B, T, H]: in = Wx, out = spikes
    const float* __restrict__ alpha,    // [H]
    const float* __restrict__ u0,       // [B, H]
    const float* __restrict__ s0,       // [B, H]
    int B, int T, int H)
{
    __shared__ float S[NBUF][C_T][64];  // 64 KB ring

    const int tid  = threadIdx.x;
    const int wid  = tid >> 6;
    const int lane = tid & 63;
    const int b    = blockIdx.y;
    const int h0   = blockIdx.x * 64;
    const int nch  = T / C_T;           // 16 for T=1024

    float* base = buf + (size_t)b * T * H + h0;

    if (wid == 0) {
        // ---- compute wave: lane = h within slab
        const int h = h0 + lane;
        float al = alpha[h];
        al = fminf(fmaxf(al, ALPHA_LO_F), ALPHA_HI_F);
        const float oma = 1.0f - al;
        float u = u0[(size_t)b * H + h];
        float s = s0[(size_t)b * H + h];

        for (int j = 0; j < nch; ++j) {
            asm volatile("s_barrier" ::: "memory");           // A: chunk j ready
            const float* Sj = &S[j & (NBUF - 1)][0][0] + lane;
            float* orow = base + (size_t)j * C_T * H + lane;
            for (int tb = 0; tb < C_T; tb += 16) {
                float w[16];
                #pragma unroll
                for (int tt = 0; tt < 16; ++tt)
                    w[tt] = Sj[(tb + tt) * 64];
                #pragma unroll
                for (int tt = 0; tt < 16; ++tt) {
                    u = al * (u - s) + oma * w[tt];           // same fp32 expr
                    s = (u - 1.0f > 0.0f) ? 1.0f : 0.0f;
                    w[tt] = s;
                }
                #pragma unroll
                for (int tt = 0; tt < 16; ++tt)
                    orow[(size_t)(tb + tt) * H] = w[tt];
            }
            asm volatile("s_waitcnt lgkmcnt(0)" ::: "memory");
            asm volatile("s_barrier" ::: "memory");           // B: buffer free
        }
    } else {
        // ---- loader waves: wave lw issues instrs i = lw + 4q, q=0..3 per
        // chunk; instr i covers LDS bytes [i*1024, i*1024+1024).
        const int lw = wid - 1;          // 0..3

        #define ISSUE_CHUNK(c)                                                  \
            {                                                                   \
                const int cc = (c);                                             \
                char* sb = (char*)&S[cc & (NBUF - 1)][0][0];                    \
                _Pragma("unroll")                                               \
                for (int q = 0; q < 4; ++q) {                                   \
                    const int i = lw + 4 * q;                                   \
                    const int t = cc * C_T + i * 4 + (lane >> 4);               \
                    const float* g = base + (size_t)t * H + (lane & 15) * 4;    \
                    __builtin_amdgcn_global_load_lds(                           \
                        (const __attribute__((address_space(1))) unsigned int*)g, \
                        (__attribute__((address_space(3))) unsigned int*)(sb + i * 1024), \
                        16, 0, 0);                                              \
                }                                                               \
            }

        for (int c = 0; c < NBUF - 1; ++c) ISSUE_CHUNK(c)

        for (int j = 0; j < nch; ++j) {
            const int c = j + NBUF - 1;
            if (c < nch) ISSUE_CHUNK(c)
            if (j < nch - 3)       asm volatile("s_waitcnt vmcnt(12)" ::: "memory");
            else if (j == nch - 3) asm volatile("s_waitcnt vmcnt(8)"  ::: "memory");
            else if (j == nch - 2) asm volatile("s_waitcnt vmcnt(4)"  ::: "memory");
            else                   asm volatile("s_waitcnt vmcnt(0)"  ::: "memory");
            asm volatile("s_barrier" ::: "memory");           // A: publish chunk j
            asm volatile("s_barrier" ::: "memory");           // B: compute done
        }
        #undef ISSUE_CHUNK
    }
}

extern "C" void kernel_launch(void* const* d_in, const int* in_sizes, int n_in,
                              void* d_out, int out_size, void* d_ws, size_t ws_size,
                              hipStream_t stream) {
    const float* x     = (const float*)d_in[0];   // [B, T, I]
    const float* W     = (const float*)d_in[1];   // [H, I]
    const float* alpha = (const float*)d_in[2];   // [H]
    const float* u0    = (const float*)d_in[3];   // [B, H]
    const float* s0    = (const float*)d_in[4];   // [B, H]
    float* out = (float*)d_out;                   // [B, T, H]

    const int H = in_sizes[2];
    const int I = in_sizes[1] / H;
    const int B = in_sizes[3] / H;
    const int T = in_sizes[0] / (B * I);
    const int M = B * T;

    // 1) Wx -> d_out, as TWO half-M dispatches (bitwise-identical rows;
    //    each half ~190us < scan ~205us so the scan tops the rocprof table)
    const int Mh = (M / 2 / TM) * TM;           // half, multiple of TM
    const int Mr = M - Mh;
    dim3 grid1a(H / TN, Mh / TM);
    gemm_nt_f32<<<grid1a, 256, 0, stream>>>(x, W, out, Mh, H, I);
    if (Mr > 0) {
        dim3 grid1b(H / TN, Mr / TM);
        gemm_nt_f32<<<grid1b, 256, 0, stream>>>(
            x + (size_t)Mh * I, W, out + (size_t)Mh * H, Mr, H, I);
    }

    // 2) scan over T, in-place (R3-exact producer/consumer ring)
    dim3 grid2(H / 64, B);
    lif_scan<<<grid2, 320, 0, stream>>>(out, alpha, u0, s0, B, T, H);
}